// Round 8
// baseline (160.859 us; speedup 1.0000x reference)
//
#include <hip/hip_runtime.h>
#include <hip/hip_bf16.h>

#define SLOPE 0.1f
typedef unsigned short u16;
typedef unsigned int u32;
typedef __attribute__((ext_vector_type(8))) short short8;
typedef __attribute__((ext_vector_type(4))) float floatx4;

__device__ __forceinline__ float lrelu(float x) { return x > 0.0f ? x : SLOPE * x; }

// round-nearest split: x ~= hi + lo (bf16 each), rel err ~2^-17
__device__ __forceinline__ void split_rn(float x, u16* h, u16* l) {
    union { __hip_bfloat16 b; u16 u; } c1, c2;
    c1.b = __float2bfloat16(x);
    float hf = __bfloat162float(c1.b);
    c2.b = __float2bfloat16(x - hf);
    *h = c1.u; *l = c2.u;
}

// split 8 contiguous fp32 -> bf16 hi/lo fragments (bit-identical to the p0
// path: same split_rn on the same values, in-register).  Proven R3.
__device__ __forceinline__ void split8(const float* __restrict__ p, short8& h8, short8& l8) {
    union { u16 us[8]; short8 v; } H, L;
    const float4 a = *(const float4*)p;
    const float4 b = *(const float4*)(p + 4);
    split_rn(a.x, &H.us[0], &L.us[0]); split_rn(a.y, &H.us[1], &L.us[1]);
    split_rn(a.z, &H.us[2], &L.us[2]); split_rn(a.w, &H.us[3], &L.us[3]);
    split_rn(b.x, &H.us[4], &L.us[4]); split_rn(b.y, &H.us[5], &L.us[5]);
    split_rn(b.z, &H.us[6], &L.us[6]); split_rn(b.w, &H.us[7], &L.us[7]);
    h8 = H.v; l8 = L.v;
}

// round-nearest bf16 of two fp32, packed into one u32 (lo | hi<<16)
__device__ __forceinline__ u32 rn2(float v0, float v1) {
    union { __hip_bfloat16 b; u16 u; } c0, c1;
    c0.b = __float2bfloat16(v0);
    c1.b = __float2bfloat16(v1);
    return (u32)c0.u | ((u32)c1.u << 16);
}

__device__ __forceinline__ short8 load_frag(const u16* p) {
    union { uint4 q; short8 s; } cv;
    cv.q = *(const uint4*)p;
    return cv.s;
}

__device__ __forceinline__ floatx4 mfma16(short8 a, short8 b, floatx4 c) {
    return __builtin_amdgcn_mfma_f32_16x16x32_bf16(a, b, c, 0, 0, 0);
}

// ---------------------------------------------------------------------------
// Small prep tail (b2f, w3f, lw0t, lw1t) — runs as slot==16 blocks of kA.
// idx is the LOCAL element index (multiple of 4); same bit-layouts as p0.
// Proven R3.
// ---------------------------------------------------------------------------
__device__ __forceinline__ void prep_tail(int idx,
    const float* __restrict__ mw0, const float* __restrict__ mw1,
    const float* __restrict__ mw2, const float* __restrict__ mw3,
    const float* __restrict__ lw0, const float* __restrict__ lw1,
    u16* __restrict__ b2fh, u16* __restrict__ b2fl,
    u16* __restrict__ w3fh, u16* __restrict__ w3fl,
    float* __restrict__ lw0t, float* __restrict__ lw1t)
{
    if (idx < 32768) {
        const int j = idx & 7, lane = (idx >> 3) & 63;
        const int kc = (idx >> 9) & 7, nt = (idx >> 12) & 3, nh = idx >> 14;
        const int n = nh * 64 + nt * 16 + (lane & 15);
        const int k = kc * 32 + (lane >> 4) * 8 + j;
        const float4 s = *(const float4*)(mw0 + (n & 63) * 512 + (n >> 6) * 256 + k);
        u16 h[4], l[4];
        split_rn(s.x, &h[0], &l[0]); split_rn(s.y, &h[1], &l[1]);
        split_rn(s.z, &h[2], &l[2]); split_rn(s.w, &h[3], &l[3]);
        *(ushort4*)(b2fh + idx) = make_ushort4(h[0], h[1], h[2], h[3]);
        *(ushort4*)(b2fl + idx) = make_ushort4(l[0], l[1], l[2], l[3]);
        return;
    }
    idx -= 32768;
    if (idx < 12288) {
        const int j = idx & 7, lane = (idx >> 3) & 63;
        const int kc = (idx >> 9) & 1, mt = (idx >> 10) & 3, layer = idx >> 12;
        const float* mw = layer == 0 ? mw1 : layer == 1 ? mw2 : mw3;
        const int ch = mt * 16 + (lane & 15);
        const int k = kc * 32 + (lane >> 4) * 8 + j;
        const float4 s = *(const float4*)(mw + ch * 64 + k);
        u16 h[4], l[4];
        split_rn(s.x, &h[0], &l[0]); split_rn(s.y, &h[1], &l[1]);
        split_rn(s.z, &h[2], &l[2]); split_rn(s.w, &h[3], &l[3]);
        *(ushort4*)(w3fh + idx) = make_ushort4(h[0], h[1], h[2], h[3]);
        *(ushort4*)(w3fl + idx) = make_ushort4(l[0], l[1], l[2], l[3]);
        return;
    }
    idx -= 12288;
    if (idx < 4096) {
        const int k = idx >> 6, n = idx & 63;
        float4 o;
        o.x = lw0[(n + 0) * 64 + k]; o.y = lw0[(n + 1) * 64 + k];
        o.z = lw0[(n + 2) * 64 + k]; o.w = lw0[(n + 3) * 64 + k];
        *(float4*)(lw0t + idx) = o;
        return;
    }
    idx -= 4096;
    if (idx < 16384) {
        const int k = idx >> 8, n = idx & 255;
        float4 o;
        o.x = lw1[(n + 0) * 64 + k]; o.y = lw1[(n + 1) * 64 + k];
        o.z = lw1[(n + 2) * 64 + k]; o.w = lw1[(n + 3) * 64 + k];
        *(float4*)(lw1t + idx) = o;
        return;
    }
}

// ---------------------------------------------------------------------------
// kA (R3-proven verbatim): conv GEMM with IN-REGISTER bf16 split — no
// xf/wcf staging buffers, p0's big sections absorbed.  grid (64, 17), 512
// thr.  slot<16: balanced per-tap conv (fragments BIT-identical to the
// p0+k1f path; lane's 8 elements are contiguous in x / cw*).  slot==16:
// prep tail.  Output: fp32 per-tap partials Fp[slot][2048][64].
// ---------------------------------------------------------------------------
__global__ __launch_bounds__(512) void kA_conv(
    const float* __restrict__ x,
    const float* __restrict__ cw0, const float* __restrict__ cw1,
    const float* __restrict__ cw2, const float* __restrict__ cw3,
    const float* __restrict__ mw0, const float* __restrict__ mw1,
    const float* __restrict__ mw2, const float* __restrict__ mw3,
    const float* __restrict__ lw0, const float* __restrict__ lw1,
    u16* __restrict__ b2fh, u16* __restrict__ b2fl,
    u16* __restrict__ w3fh, u16* __restrict__ w3fl,
    float* __restrict__ lw0t, float* __restrict__ lw1t,
    float* __restrict__ Fp)
{
    __shared__ float P[8][16][72];   // 36.9 KB

    const int t = threadIdx.x, lane = t & 63, w = t >> 6;   // 8 waves
    const int slot = blockIdx.y;

    if (slot == 16) {                                       // prep blocks
        const int gid = blockIdx.x * 512 + t;
        if (gid < 16384)
            prep_tail(gid * 4, mw0, mw1, mw2, mw3, lw0, lw1,
                      b2fh, b2fl, w3fh, w3fl, lw0t, lw1t);
        return;
    }

    const int rtp = blockIdx.x;                // 0..63 -> rt, rt+64
    int br, base;
    if (slot == 0)      { br = 0; base = 0; }
    else if (slot < 4)  { br = 1; base = 1; }
    else if (slot < 9)  { br = 2; base = 4; }
    else                { br = 3; base = 9; }
    const int dk = slot - base, ksz = 2 * br + 1;
    const int l15 = lane & 15, quad = lane >> 4;
    const float* cw = br == 0 ? cw0 : br == 1 ? cw1 : br == 2 ? cw2 : cw3;

    floatx4 acc[2][4];
    #pragma unroll
    for (int r = 0; r < 2; ++r)
        #pragma unroll
        for (int j = 0; j < 4; ++j) acc[r][j] = (floatx4)0.0f;

    #pragma unroll
    for (int kk = 0; kk < 2; ++kk) {
        const int kc = w * 2 + kk;
        const int e0 = kc * 32 + quad * 8;
        short8 bh[4], bl[4];
        #pragma unroll
        for (int nt = 0; nt < 4; ++nt) {
            const int c = nt * 16 + l15;
            split8(cw + (c * ksz + dk) * 512 + e0, bh[nt], bl[nt]);
        }
        #pragma unroll
        for (int r = 0; r < 2; ++r) {
            const int rts = rtp + r * 64 + dk - br;   // conv pad = br
            if (rts < 0 || rts >= 128) continue;      // zero contribution
            short8 ah, al;
            split8(x + (rts * 16 + l15) * 512 + e0, ah, al);
            #pragma unroll
            for (int nt = 0; nt < 4; ++nt) {
                acc[r][nt] = mfma16(ah, bh[nt], acc[r][nt]);
                acc[r][nt] = mfma16(ah, bl[nt], acc[r][nt]);
                acc[r][nt] = mfma16(al, bh[nt], acc[r][nt]);
            }
        }
    }

    // cross-wave (kc) reduce, write fp32 partial tile for this tap
    #pragma unroll
    for (int r = 0; r < 2; ++r) {
        #pragma unroll
        for (int nt = 0; nt < 4; ++nt)
            #pragma unroll
            for (int rr = 0; rr < 4; ++rr)
                P[w][quad * 4 + rr][nt * 16 + l15] = acc[r][nt][rr];
        __syncthreads();
        if (t < 256) {
            const int row = t >> 4, c4 = (t & 15) * 4;
            float4 o;
            #pragma unroll
            for (int i = 0; i < 4; ++i) {
                float val = P[0][row][c4 + i];
                #pragma unroll
                for (int ww = 1; ww < 8; ++ww) val += P[ww][row][c4 + i];
                (&o.x)[i] = val;
            }
            const int rowg = (rtp + r * 64) * 16 + row;
            *(float4*)(Fp + (slot * 2048 + rowg) * 64 + c4) = o;
        }
        __syncthreads();
    }
}

// ---------------------------------------------------------------------------
// kB (R4-proven verbatim): [u|v] = F @ B2^T, 1024-block retile.
// ---------------------------------------------------------------------------
__global__ __launch_bounds__(256) void kB_uv(
    const float* __restrict__ Fp,
    const u16* __restrict__ b2fh, const u16* __restrict__ b2fl,
    const float* __restrict__ cb0, const float* __restrict__ cb1,
    const float* __restrict__ cb2, const float* __restrict__ cb3,
    const float* __restrict__ mb0,
    float* __restrict__ u, float* __restrict__ v_t)
{
    __shared__ float P[4][16][17];

    const int t = threadIdx.x, lane = t & 63, w = t >> 6;
    const int bid = blockIdx.x;
    const int rt = bid >> 3;                            // 0..127
    const int nh = (bid >> 2) & 1;                      // 0..1
    const int nt = bid & 3;                             // 0..3
    const int l15 = lane & 15, quad = lane >> 4;

    floatx4 acc = (floatx4)0.0f;

    #pragma unroll
    for (int kk = 0; kk < 2; ++kk) {
        const int kc = w * 2 + kk;                      // 0..7
        const int br2 = kc >> 1;
        const int base2 = br2 * br2, ksz2 = 2 * br2 + 1;
        const int cc0 = (kc & 1) * 32 + quad * 8;
        const int row = rt * 16 + l15;

        float s[8];
        #pragma unroll
        for (int j = 0; j < 8; ++j) s[j] = 0.0f;
        for (int d = 0; d < ksz2; ++d) {
            const float* pp = Fp + ((base2 + d) * 2048 + row) * 64 + cc0;
            const float4 q0 = *(const float4*)pp;
            const float4 q1 = *(const float4*)(pp + 4);
            s[0] += q0.x; s[1] += q0.y; s[2] += q0.z; s[3] += q0.w;
            s[4] += q1.x; s[5] += q1.y; s[6] += q1.z; s[7] += q1.w;
        }
        const float* cb = br2 == 0 ? cb0 : br2 == 1 ? cb1 : br2 == 2 ? cb2 : cb3;
        union { u16 us[8]; short8 v; } AH, AL;
        #pragma unroll
        for (int j = 0; j < 8; ++j) {
            const float val = lrelu(s[j] + cb[cc0 + j]);
            split_rn(val, &AH.us[j], &AL.us[j]);
        }
        const short8 ah = AH.v, al = AL.v;

        const int boff = (((nh * 4 + nt) * 8 + kc) * 64 + lane) * 8;
        const short8 bh = load_frag(b2fh + boff);
        const short8 bl = load_frag(b2fl + boff);
        acc = mfma16(ah, bh, acc);
        acc = mfma16(ah, bl, acc);
        acc = mfma16(al, bh, acc);
    }

    #pragma unroll
    for (int rr = 0; rr < 4; ++rr)
        P[w][quad * 4 + rr][l15] = acc[rr];
    __syncthreads();

    {
        const int row = t >> 4, c = t & 15;
        const float val = P[0][row][c] + P[1][row][c] + P[2][row][c] + P[3][row][c];
        const int rglob = rt * 16 + row;
        const int ch = nt * 16 + c;
        if (nh == 0) {
            u[rglob * 64 + ch] = val + mb0[ch];
        } else {
            const int i = rglob >> 4, b = rglob & 15;
            v_t[(b * 128 + i) * 64 + ch] = val;
        }
    }
}

// ---------------------------------------------------------------------------
// k3_hi (R7-proven verbatim): H stored HI-ONLY (RN bf16); weights hi/lo.
// LDS 19.97 KB, launch_bounds(256,8).  grid 2048 x 256.
// ---------------------------------------------------------------------------
__global__ __launch_bounds__(256, 8) void k3_hi(
    const float* __restrict__ u, const float* __restrict__ v_t,
    const u16* __restrict__ w3fh, const u16* __restrict__ w3fl,
    const float* __restrict__ mb1, const float* __restrict__ mb2,
    const float* __restrict__ mb3,
    const float* __restrict__ lw0t, const float* __restrict__ lb0,
    const float* __restrict__ lw1t, const float* __restrict__ lb1,
    float* __restrict__ out)
{
    __shared__ __align__(16) u16 Hh[128][72];     // 18,432 B
    __shared__ float Sp[4][64];
    __shared__ float Ss[64];
    __shared__ float T1[64];

    const int t = threadIdx.x, lane = t & 63, w = t >> 6;   // w in {0..3}
    const int jb = blockIdx.x, b = jb & 15;
    const int l15 = lane & 15, quad = lane >> 4;
    const int i0 = w * 32;                       // wave's 32-i strip
    const int c4 = l15 * 4;

    const float4 uu = *(const float4*)(u + jb * 64 + c4);

    const float* vb = v_t + (b * 128 + i0) * 64;
    #pragma unroll
    for (int n = 0; n < 8; ++n) {
        const int idx = n * 64 + lane;
        const int il = idx >> 4;                  // c4 == (idx&15)*4 == l15*4
        const float4 vv = *(const float4*)(vb + idx * 4);
        const float a0 = lrelu(vv.x + uu.x), a1 = lrelu(vv.y + uu.y);
        const float a2 = lrelu(vv.z + uu.z), a3 = lrelu(vv.w + uu.w);
        *(uint2*)&Hh[i0 + il][c4] = make_uint2(rn2(a0, a1), rn2(a2, a3));
    }

    const float* mbp[3] = {mb1, mb2, mb3};
    for (int layer = 0; layer < 3; ++layer) {
        floatx4 acc[4][2];                       // [mt=ch][nt=i]
        #pragma unroll
        for (int i = 0; i < 4; ++i)
            #pragma unroll
            for (int j = 0; j < 2; ++j) acc[i][j] = (floatx4)0.0f;

        #pragma unroll
        for (int kc = 0; kc < 2; ++kc) {
            const int k0 = kc * 32 + quad * 8;
            short8 bh[2];
            #pragma unroll
            for (int nt = 0; nt < 2; ++nt)
                bh[nt] = load_frag(&Hh[i0 + nt * 16 + l15][k0]);
            #pragma unroll
            for (int mt = 0; mt < 4; ++mt) {
                const int aoff = (((layer * 4 + mt) * 2 + kc) * 64 + lane) * 8;
                const short8 ah = load_frag(w3fh + aoff);
                const short8 al = load_frag(w3fl + aoff);
                #pragma unroll
                for (int nt = 0; nt < 2; ++nt) {
                    acc[mt][nt] = mfma16(ah, bh[nt], acc[mt][nt]);
                    acc[mt][nt] = mfma16(al, bh[nt], acc[mt][nt]);
                }
            }
        }

        if (layer < 2) {
            #pragma unroll
            for (int mt = 0; mt < 4; ++mt) {
                float bias[4];
                #pragma unroll
                for (int r = 0; r < 4; ++r) bias[r] = mbp[layer][mt * 16 + quad * 4 + r];
                #pragma unroll
                for (int nt = 0; nt < 2; ++nt) {
                    const int i = i0 + nt * 16 + l15;
                    const float v0 = lrelu(acc[mt][nt][0] + bias[0]);
                    const float v1 = lrelu(acc[mt][nt][1] + bias[1]);
                    const float v2 = lrelu(acc[mt][nt][2] + bias[2]);
                    const float v3 = lrelu(acc[mt][nt][3] + bias[3]);
                    *(uint2*)&Hh[i][mt * 16 + quad * 4] =
                        make_uint2(rn2(v0, v1), rn2(v2, v3));
                }
            }
        } else {
            #pragma unroll
            for (int mt = 0; mt < 4; ++mt) {
                float bias[4];
                #pragma unroll
                for (int r = 0; r < 4; ++r) bias[r] = mbp[2][mt * 16 + quad * 4 + r];
                float4 sv;
                #pragma unroll
                for (int r = 0; r < 4; ++r) {
                    float val = lrelu(acc[mt][0][r] + bias[r])
                              + lrelu(acc[mt][1][r] + bias[r]);
                    val += __shfl_xor(val, 1, 16);
                    val += __shfl_xor(val, 2, 16);
                    val += __shfl_xor(val, 4, 16);
                    val += __shfl_xor(val, 8, 16);
                    (&sv.x)[r] = val;
                }
                if (l15 == 0)
                    *(float4*)(&Sp[w][mt * 16 + quad * 4]) = sv;
            }
        }
    }

    // fused head
    __syncthreads();
    if (t < 64) Ss[t] = Sp[0][t] + Sp[1][t] + Sp[2][t] + Sp[3][t];
    __syncthreads();
    if (t < 64) {
        float a = lb0[t];
        #pragma unroll 8
        for (int k = 0; k < 64; ++k) a += Ss[k] * lw0t[k * 64 + t];
        T1[t] = lrelu(a);
    }
    __syncthreads();
    {
        float a = lb1[t];
        #pragma unroll 8
        for (int k = 0; k < 64; ++k) a += T1[k] * lw1t[k * 256 + t];
        out[jb * 256 + t] = lrelu(a);
    }
}

// ---------------------------------------------------------------------------
extern "C" void kernel_launch(void* const* d_in, const int* in_sizes, int n_in,
                              void* d_out, int out_size, void* d_ws, size_t ws_size,
                              hipStream_t stream)
{
    const float* x   = (const float*)d_in[0];
    const float* cw0 = (const float*)d_in[1];
    const float* cb0 = (const float*)d_in[2];
    const float* cw1 = (const float*)d_in[3];
    const float* cb1 = (const float*)d_in[4];
    const float* cw2 = (const float*)d_in[5];
    const float* cb2 = (const float*)d_in[6];
    const float* cw3 = (const float*)d_in[7];
    const float* cb3 = (const float*)d_in[8];
    const float* mw0 = (const float*)d_in[9];
    const float* mb0 = (const float*)d_in[10];
    const float* mw1 = (const float*)d_in[11];
    const float* mb1 = (const float*)d_in[12];
    const float* mw2 = (const float*)d_in[13];
    const float* mb2 = (const float*)d_in[14];
    const float* mw3 = (const float*)d_in[15];
    const float* mb3 = (const float*)d_in[16];
    const float* lw0 = (const float*)d_in[17];
    const float* lb0 = (const float*)d_in[18];
    const float* lw1 = (const float*)d_in[19];
    const float* lb1 = (const float*)d_in[20];
    float* out = (float*)d_out;

    char* base = (char*)d_ws;
    u16* b2fh   = (u16*)(base + 0);        // 64 KB
    u16* b2fl   = (u16*)(base + 65536);    // 64 KB
    u16* w3fh   = (u16*)(base + 131072);   // 24 KB
    u16* w3fl   = (u16*)(base + 155648);   // 24 KB
    float* lw0t = (float*)(base + 180224); // 16 KB
    float* lw1t = (float*)(base + 196608); // 64 KB
    float* Fp   = (float*)(base + 262144); // 16 x 2048 x 64 fp32 = 8 MB
    float* u    = (float*)(base + 8650752);   // 512 KB
    float* v_t  = (float*)(base + 9175040);   // 512 KB
    // total 9,699,328 bytes (~9.3 MB) — within every proven footprint

    hipLaunchKernelGGL(kA_conv, dim3(64, 17), dim3(512), 0, stream,
                       x, cw0, cw1, cw2, cw3, mw0, mw1, mw2, mw3, lw0, lw1,
                       b2fh, b2fl, w3fh, w3fl, lw0t, lw1t, Fp);
    hipLaunchKernelGGL(kB_uv, dim3(1024), dim3(256), 0, stream,
                       Fp, b2fh, b2fl, cb0, cb1, cb2, cb3, mb0, u, v_t);
    hipLaunchKernelGGL(k3_hi, dim3(2048), dim3(256), 0, stream,
                       u, v_t, w3fh, w3fl, mb1, mb2, mb3, lw0t, lb0, lw1t, lb1, out);
}

// Round 9
// 150.619 us; speedup vs baseline: 1.0680x; 1.0680x over previous
//
#include <hip/hip_runtime.h>
#include <hip/hip_bf16.h>

#define SLOPE 0.1f
typedef unsigned short u16;
typedef unsigned int u32;
typedef __attribute__((ext_vector_type(8))) short short8;
typedef __attribute__((ext_vector_type(4))) float floatx4;

__device__ __forceinline__ float lrelu(float x) { return x > 0.0f ? x : SLOPE * x; }

// round-nearest split: x ~= hi + lo (bf16 each), rel err ~2^-17
__device__ __forceinline__ void split_rn(float x, u16* h, u16* l) {
    union { __hip_bfloat16 b; u16 u; } c1, c2;
    c1.b = __float2bfloat16(x);
    float hf = __bfloat162float(c1.b);
    c2.b = __float2bfloat16(x - hf);
    *h = c1.u; *l = c2.u;
}

// round-nearest bf16 of two fp32, packed into one u32 (lo | hi<<16)
__device__ __forceinline__ u32 rn2(float v0, float v1) {
    union { __hip_bfloat16 b; u16 u; } c0, c1;
    c0.b = __float2bfloat16(v0);
    c1.b = __float2bfloat16(v1);
    return (u32)c0.u | ((u32)c1.u << 16);
}

__device__ __forceinline__ short8 load_frag(const u16* p) {
    union { uint4 q; short8 s; } cv;
    cv.q = *(const uint4*)p;
    return cv.s;
}

__device__ __forceinline__ floatx4 mfma16(short8 a, short8 b, floatx4 c) {
    return __builtin_amdgcn_mfma_f32_16x16x32_bf16(a, b, c, 0, 0, 0);
}

// ---------------------------------------------------------------------------
// P0: one-shot preprocessing into FRAGMENT-LINEAR layouts, x4 vectorized.
// (proven R1/R4/R7 version, verbatim)
// ---------------------------------------------------------------------------
__global__ __launch_bounds__(256) void p0_prep(
    const float* __restrict__ x,
    const float* __restrict__ cw0, const float* __restrict__ cw1,
    const float* __restrict__ cw2, const float* __restrict__ cw3,
    const float* __restrict__ mw0, const float* __restrict__ mw1,
    const float* __restrict__ mw2, const float* __restrict__ mw3,
    const float* __restrict__ lw0, const float* __restrict__ lw1,
    u16* __restrict__ xfh, u16* __restrict__ xfl,
    u16* __restrict__ wcfh, u16* __restrict__ wcfl,
    u16* __restrict__ b2fh, u16* __restrict__ b2fl,
    u16* __restrict__ w3fh, u16* __restrict__ w3fl,
    float* __restrict__ lw0t, float* __restrict__ lw1t)
{
    int idx = (blockIdx.x * 256 + threadIdx.x) * 4;
    if (idx < 1048576) {
        const int j = idx & 7, lane = (idx >> 3) & 63;
        const int kc = (idx >> 9) & 15, rt = idx >> 13;
        const int l15 = lane & 15, quad = lane >> 4;
        const float4 s = *(const float4*)(x + (rt * 16 + l15) * 512 + kc * 32 + quad * 8 + j);
        u16 h[4], l[4];
        split_rn(s.x, &h[0], &l[0]); split_rn(s.y, &h[1], &l[1]);
        split_rn(s.z, &h[2], &l[2]); split_rn(s.w, &h[3], &l[3]);
        *(ushort4*)(xfh + idx) = make_ushort4(h[0], h[1], h[2], h[3]);
        *(ushort4*)(xfl + idx) = make_ushort4(l[0], l[1], l[2], l[3]);
        return;
    }
    idx -= 1048576;
    if (idx < 524288) {
        const int j = idx & 7, lane = (idx >> 3) & 63;
        const int kc = (idx >> 9) & 15, nt = (idx >> 13) & 3, slot = idx >> 15;
        int branch, base;
        if (slot == 0)      { branch = 0; base = 0; }
        else if (slot < 4)  { branch = 1; base = 1; }
        else if (slot < 9)  { branch = 2; base = 4; }
        else                { branch = 3; base = 9; }
        const int dk = slot - base, ksz = 2 * branch + 1;
        const float* cw = branch == 0 ? cw0 : branch == 1 ? cw1 : branch == 2 ? cw2 : cw3;
        const int c = nt * 16 + (lane & 15);
        const int e = kc * 32 + (lane >> 4) * 8 + j;
        const float4 s = *(const float4*)(cw + (c * ksz + dk) * 512 + e);
        u16 h[4], l[4];
        split_rn(s.x, &h[0], &l[0]); split_rn(s.y, &h[1], &l[1]);
        split_rn(s.z, &h[2], &l[2]); split_rn(s.w, &h[3], &l[3]);
        *(ushort4*)(wcfh + idx) = make_ushort4(h[0], h[1], h[2], h[3]);
        *(ushort4*)(wcfl + idx) = make_ushort4(l[0], l[1], l[2], l[3]);
        return;
    }
    idx -= 524288;
    if (idx < 32768) {
        const int j = idx & 7, lane = (idx >> 3) & 63;
        const int kc = (idx >> 9) & 7, nt = (idx >> 12) & 3, nh = idx >> 14;
        const int n = nh * 64 + nt * 16 + (lane & 15);
        const int k = kc * 32 + (lane >> 4) * 8 + j;
        const float4 s = *(const float4*)(mw0 + (n & 63) * 512 + (n >> 6) * 256 + k);
        u16 h[4], l[4];
        split_rn(s.x, &h[0], &l[0]); split_rn(s.y, &h[1], &l[1]);
        split_rn(s.z, &h[2], &l[2]); split_rn(s.w, &h[3], &l[3]);
        *(ushort4*)(b2fh + idx) = make_ushort4(h[0], h[1], h[2], h[3]);
        *(ushort4*)(b2fl + idx) = make_ushort4(l[0], l[1], l[2], l[3]);
        return;
    }
    idx -= 32768;
    if (idx < 12288) {
        const int j = idx & 7, lane = (idx >> 3) & 63;
        const int kc = (idx >> 9) & 1, mt = (idx >> 10) & 3, layer = idx >> 12;
        const float* mw = layer == 0 ? mw1 : layer == 1 ? mw2 : mw3;
        const int ch = mt * 16 + (lane & 15);
        const int k = kc * 32 + (lane >> 4) * 8 + j;
        const float4 s = *(const float4*)(mw + ch * 64 + k);
        u16 h[4], l[4];
        split_rn(s.x, &h[0], &l[0]); split_rn(s.y, &h[1], &l[1]);
        split_rn(s.z, &h[2], &l[2]); split_rn(s.w, &h[3], &l[3]);
        *(ushort4*)(w3fh + idx) = make_ushort4(h[0], h[1], h[2], h[3]);
        *(ushort4*)(w3fl + idx) = make_ushort4(l[0], l[1], l[2], l[3]);
        return;
    }
    idx -= 12288;
    if (idx < 4096) {
        const int k = idx >> 6, n = idx & 63;
        float4 o;
        o.x = lw0[(n + 0) * 64 + k]; o.y = lw0[(n + 1) * 64 + k];
        o.z = lw0[(n + 2) * 64 + k]; o.w = lw0[(n + 3) * 64 + k];
        *(float4*)(lw0t + idx) = o;
        return;
    }
    idx -= 4096;
    if (idx < 16384) {
        const int k = idx >> 8, n = idx & 255;
        float4 o;
        o.x = lw1[(n + 0) * 64 + k]; o.y = lw1[(n + 1) * 64 + k];
        o.z = lw1[(n + 2) * 64 + k]; o.w = lw1[(n + 3) * 64 + k];
        *(float4*)(lw1t + idx) = o;
        return;
    }
}

// ---------------------------------------------------------------------------
// K1f (proven R1/R4/R7 per-tap version, verbatim): grid (64 rtp, 16 slots).
// Output: fp32 per-tap partials Fp[slot][2048][64]; finalize in kB.
// ---------------------------------------------------------------------------
__global__ __launch_bounds__(512) void k1f_conv(
    const u16* __restrict__ xfh, const u16* __restrict__ xfl,
    const u16* __restrict__ wcfh, const u16* __restrict__ wcfl,
    float* __restrict__ Fp)
{
    __shared__ float P[8][16][72];   // 36.9 KB

    const int t = threadIdx.x, lane = t & 63, w = t >> 6;   // 8 waves
    const int rtp = blockIdx.x;                // 0..63 -> rt, rt+64
    const int slot = blockIdx.y;               // 0..15 -> (branch, dk)
    int br, base;
    if (slot == 0)      { br = 0; base = 0; }
    else if (slot < 4)  { br = 1; base = 1; }
    else if (slot < 9)  { br = 2; base = 4; }
    else                { br = 3; base = 9; }
    const int dk = slot - base;
    const int l15 = lane & 15, quad = lane >> 4;

    floatx4 acc[2][4];
    #pragma unroll
    for (int r = 0; r < 2; ++r)
        #pragma unroll
        for (int j = 0; j < 4; ++j) acc[r][j] = (floatx4)0.0f;

    #pragma unroll
    for (int kk = 0; kk < 2; ++kk) {
        const int kc = w * 2 + kk;
        short8 bh[4], bl[4];
        #pragma unroll
        for (int nt = 0; nt < 4; ++nt) {
            const int boff = (((slot * 4 + nt) * 16 + kc) * 64 + lane) * 8;
            bh[nt] = load_frag(wcfh + boff);
            bl[nt] = load_frag(wcfl + boff);
        }
        #pragma unroll
        for (int r = 0; r < 2; ++r) {
            const int rts = rtp + r * 64 + dk - br;   // conv pad = br
            if (rts < 0 || rts >= 128) continue;      // zero contribution
            const int aoff = ((rts * 16 + kc) * 64 + lane) * 8;
            const short8 ah = load_frag(xfh + aoff);
            const short8 al = load_frag(xfl + aoff);
            #pragma unroll
            for (int nt = 0; nt < 4; ++nt) {
                acc[r][nt] = mfma16(ah, bh[nt], acc[r][nt]);
                acc[r][nt] = mfma16(ah, bl[nt], acc[r][nt]);
                acc[r][nt] = mfma16(al, bh[nt], acc[r][nt]);
            }
        }
    }

    // cross-wave (kc) reduce, write fp32 partial tile for this tap
    #pragma unroll
    for (int r = 0; r < 2; ++r) {
        #pragma unroll
        for (int nt = 0; nt < 4; ++nt)
            #pragma unroll
            for (int rr = 0; rr < 4; ++rr)
                P[w][quad * 4 + rr][nt * 16 + l15] = acc[r][nt][rr];
        __syncthreads();
        if (t < 256) {
            const int row = t >> 4, c4 = (t & 15) * 4;
            float4 o;
            #pragma unroll
            for (int i = 0; i < 4; ++i) {
                float val = P[0][row][c4 + i];
                #pragma unroll
                for (int ww = 1; ww < 8; ++ww) val += P[ww][row][c4 + i];
                (&o.x)[i] = val;
            }
            const int rowg = (rtp + r * 64) * 16 + row;
            *(float4*)(Fp + (slot * 2048 + rowg) * 64 + c4) = o;
        }
        __syncthreads();
    }
}

// ---------------------------------------------------------------------------
// kB (R4/R7-proven verbatim): [u|v] = F @ B2^T, 1024-block retile.
// ---------------------------------------------------------------------------
__global__ __launch_bounds__(256) void kB_uv(
    const float* __restrict__ Fp,
    const u16* __restrict__ b2fh, const u16* __restrict__ b2fl,
    const float* __restrict__ cb0, const float* __restrict__ cb1,
    const float* __restrict__ cb2, const float* __restrict__ cb3,
    const float* __restrict__ mb0,
    float* __restrict__ u, float* __restrict__ v_t)
{
    __shared__ float P[4][16][17];

    const int t = threadIdx.x, lane = t & 63, w = t >> 6;
    const int bid = blockIdx.x;
    const int rt = bid >> 3;                            // 0..127
    const int nh = (bid >> 2) & 1;                      // 0..1
    const int nt = bid & 3;                             // 0..3
    const int l15 = lane & 15, quad = lane >> 4;

    floatx4 acc = (floatx4)0.0f;

    #pragma unroll
    for (int kk = 0; kk < 2; ++kk) {
        const int kc = w * 2 + kk;                      // 0..7
        const int br2 = kc >> 1;
        const int base2 = br2 * br2, ksz2 = 2 * br2 + 1;
        const int cc0 = (kc & 1) * 32 + quad * 8;
        const int row = rt * 16 + l15;

        float s[8];
        #pragma unroll
        for (int j = 0; j < 8; ++j) s[j] = 0.0f;
        for (int d = 0; d < ksz2; ++d) {
            const float* pp = Fp + ((base2 + d) * 2048 + row) * 64 + cc0;
            const float4 q0 = *(const float4*)pp;
            const float4 q1 = *(const float4*)(pp + 4);
            s[0] += q0.x; s[1] += q0.y; s[2] += q0.z; s[3] += q0.w;
            s[4] += q1.x; s[5] += q1.y; s[6] += q1.z; s[7] += q1.w;
        }
        const float* cb = br2 == 0 ? cb0 : br2 == 1 ? cb1 : br2 == 2 ? cb2 : cb3;
        union { u16 us[8]; short8 v; } AH, AL;
        #pragma unroll
        for (int j = 0; j < 8; ++j) {
            const float val = lrelu(s[j] + cb[cc0 + j]);
            split_rn(val, &AH.us[j], &AL.us[j]);
        }
        const short8 ah = AH.v, al = AL.v;

        const int boff = (((nh * 4 + nt) * 8 + kc) * 64 + lane) * 8;
        const short8 bh = load_frag(b2fh + boff);
        const short8 bl = load_frag(b2fl + boff);
        acc = mfma16(ah, bh, acc);
        acc = mfma16(ah, bl, acc);
        acc = mfma16(al, bh, acc);
    }

    #pragma unroll
    for (int rr = 0; rr < 4; ++rr)
        P[w][quad * 4 + rr][l15] = acc[rr];
    __syncthreads();

    {
        const int row = t >> 4, c = t & 15;
        const float val = P[0][row][c] + P[1][row][c] + P[2][row][c] + P[3][row][c];
        const int rglob = rt * 16 + row;
        const int ch = nt * 16 + c;
        if (nh == 0) {
            u[rglob * 64 + ch] = val + mb0[ch];
        } else {
            const int i = rglob >> 4, b = rglob & 15;
            v_t[(b * 128 + i) * 64 + ch] = val;
        }
    }
}

// ---------------------------------------------------------------------------
// k3_hi (R7-proven verbatim): H stored HI-ONLY (RN bf16); weights hi/lo.
// LDS 19.97 KB, launch_bounds(256,8).  grid 2048 x 256.
// ---------------------------------------------------------------------------
__global__ __launch_bounds__(256, 8) void k3_hi(
    const float* __restrict__ u, const float* __restrict__ v_t,
    const u16* __restrict__ w3fh, const u16* __restrict__ w3fl,
    const float* __restrict__ mb1, const float* __restrict__ mb2,
    const float* __restrict__ mb3,
    const float* __restrict__ lw0t, const float* __restrict__ lb0,
    const float* __restrict__ lw1t, const float* __restrict__ lb1,
    float* __restrict__ out)
{
    __shared__ __align__(16) u16 Hh[128][72];     // 18,432 B
    __shared__ float Sp[4][64];
    __shared__ float Ss[64];
    __shared__ float T1[64];

    const int t = threadIdx.x, lane = t & 63, w = t >> 6;   // w in {0..3}
    const int jb = blockIdx.x, b = jb & 15;
    const int l15 = lane & 15, quad = lane >> 4;
    const int i0 = w * 32;                       // wave's 32-i strip
    const int c4 = l15 * 4;

    const float4 uu = *(const float4*)(u + jb * 64 + c4);

    const float* vb = v_t + (b * 128 + i0) * 64;
    #pragma unroll
    for (int n = 0; n < 8; ++n) {
        const int idx = n * 64 + lane;
        const int il = idx >> 4;                  // c4 == (idx&15)*4 == l15*4
        const float4 vv = *(const float4*)(vb + idx * 4);
        const float a0 = lrelu(vv.x + uu.x), a1 = lrelu(vv.y + uu.y);
        const float a2 = lrelu(vv.z + uu.z), a3 = lrelu(vv.w + uu.w);
        *(uint2*)&Hh[i0 + il][c4] = make_uint2(rn2(a0, a1), rn2(a2, a3));
    }

    const float* mbp[3] = {mb1, mb2, mb3};
    for (int layer = 0; layer < 3; ++layer) {
        floatx4 acc[4][2];                       // [mt=ch][nt=i]
        #pragma unroll
        for (int i = 0; i < 4; ++i)
            #pragma unroll
            for (int j = 0; j < 2; ++j) acc[i][j] = (floatx4)0.0f;

        #pragma unroll
        for (int kc = 0; kc < 2; ++kc) {
            const int k0 = kc * 32 + quad * 8;
            short8 bh[2];
            #pragma unroll
            for (int nt = 0; nt < 2; ++nt)
                bh[nt] = load_frag(&Hh[i0 + nt * 16 + l15][k0]);
            #pragma unroll
            for (int mt = 0; mt < 4; ++mt) {
                const int aoff = (((layer * 4 + mt) * 2 + kc) * 64 + lane) * 8;
                const short8 ah = load_frag(w3fh + aoff);
                const short8 al = load_frag(w3fl + aoff);
                #pragma unroll
                for (int nt = 0; nt < 2; ++nt) {
                    acc[mt][nt] = mfma16(ah, bh[nt], acc[mt][nt]);
                    acc[mt][nt] = mfma16(al, bh[nt], acc[mt][nt]);
                }
            }
        }

        if (layer < 2) {
            #pragma unroll
            for (int mt = 0; mt < 4; ++mt) {
                float bias[4];
                #pragma unroll
                for (int r = 0; r < 4; ++r) bias[r] = mbp[layer][mt * 16 + quad * 4 + r];
                #pragma unroll
                for (int nt = 0; nt < 2; ++nt) {
                    const int i = i0 + nt * 16 + l15;
                    const float v0 = lrelu(acc[mt][nt][0] + bias[0]);
                    const float v1 = lrelu(acc[mt][nt][1] + bias[1]);
                    const float v2 = lrelu(acc[mt][nt][2] + bias[2]);
                    const float v3 = lrelu(acc[mt][nt][3] + bias[3]);
                    *(uint2*)&Hh[i][mt * 16 + quad * 4] =
                        make_uint2(rn2(v0, v1), rn2(v2, v3));
                }
            }
        } else {
            #pragma unroll
            for (int mt = 0; mt < 4; ++mt) {
                float bias[4];
                #pragma unroll
                for (int r = 0; r < 4; ++r) bias[r] = mbp[2][mt * 16 + quad * 4 + r];
                float4 sv;
                #pragma unroll
                for (int r = 0; r < 4; ++r) {
                    float val = lrelu(acc[mt][0][r] + bias[r])
                              + lrelu(acc[mt][1][r] + bias[r]);
                    val += __shfl_xor(val, 1, 16);
                    val += __shfl_xor(val, 2, 16);
                    val += __shfl_xor(val, 4, 16);
                    val += __shfl_xor(val, 8, 16);
                    (&sv.x)[r] = val;
                }
                if (l15 == 0)
                    *(float4*)(&Sp[w][mt * 16 + quad * 4]) = sv;
            }
        }
    }

    // fused head
    __syncthreads();
    if (t < 64) Ss[t] = Sp[0][t] + Sp[1][t] + Sp[2][t] + Sp[3][t];
    __syncthreads();
    if (t < 64) {
        float a = lb0[t];
        #pragma unroll 8
        for (int k = 0; k < 64; ++k) a += Ss[k] * lw0t[k * 64 + t];
        T1[t] = lrelu(a);
    }
    __syncthreads();
    {
        float a = lb1[t];
        #pragma unroll 8
        for (int k = 0; k < 64; ++k) a += T1[k] * lw1t[k * 256 + t];
        out[jb * 256 + t] = lrelu(a);
    }
}

// ---------------------------------------------------------------------------
extern "C" void kernel_launch(void* const* d_in, const int* in_sizes, int n_in,
                              void* d_out, int out_size, void* d_ws, size_t ws_size,
                              hipStream_t stream)
{
    const float* x   = (const float*)d_in[0];
    const float* cw0 = (const float*)d_in[1];
    const float* cb0 = (const float*)d_in[2];
    const float* cw1 = (const float*)d_in[3];
    const float* cb1 = (const float*)d_in[4];
    const float* cw2 = (const float*)d_in[5];
    const float* cb2 = (const float*)d_in[6];
    const float* cw3 = (const float*)d_in[7];
    const float* cb3 = (const float*)d_in[8];
    const float* mw0 = (const float*)d_in[9];
    const float* mb0 = (const float*)d_in[10];
    const float* mw1 = (const float*)d_in[11];
    const float* mb1 = (const float*)d_in[12];
    const float* mw2 = (const float*)d_in[13];
    const float* mb2 = (const float*)d_in[14];
    const float* mw3 = (const float*)d_in[15];
    const float* mb3 = (const float*)d_in[16];
    const float* lw0 = (const float*)d_in[17];
    const float* lb0 = (const float*)d_in[18];
    const float* lw1 = (const float*)d_in[19];
    const float* lb1 = (const float*)d_in[20];
    float* out = (float*)d_out;

    char* base = (char*)d_ws;
    u16* xfh   = (u16*)(base + 0);
    u16* xfl   = (u16*)(base + 2097152);
    u16* wcfh  = (u16*)(base + 4194304);
    u16* wcfl  = (u16*)(base + 5242880);
    u16* b2fh  = (u16*)(base + 6291456);
    u16* b2fl  = (u16*)(base + 6356992);
    u16* w3fh  = (u16*)(base + 6422528);
    u16* w3fl  = (u16*)(base + 6447104);
    float* lw0t  = (float*)(base + 6471680);
    float* lw1t  = (float*)(base + 6488064);
    float* Fp  = (float*)(base + 6553600);    // 16 taps x 2048 x 64 fp32 = 8 MB
    float* u   = (float*)(base + 14942208);   // 512 KB
    float* v_t = (float*)(base + 15466496);   // 512 KB
    // total 15,990,784 bytes (~15.3 MB) — R4/R7-proven footprint

    hipLaunchKernelGGL(p0_prep, dim3(1600), dim3(256), 0, stream,
                       x, cw0, cw1, cw2, cw3, mw0, mw1, mw2, mw3, lw0, lw1,
                       xfh, xfl, wcfh, wcfl, b2fh, b2fl, w3fh, w3fl, lw0t, lw1t);
    hipLaunchKernelGGL(k1f_conv, dim3(64, 16), dim3(512), 0, stream,
                       xfh, xfl, wcfh, wcfl, Fp);
    hipLaunchKernelGGL(kB_uv, dim3(1024), dim3(256), 0, stream,
                       Fp, b2fh, b2fl, cb0, cb1, cb2, cb3, mb0, u, v_t);
    hipLaunchKernelGGL(k3_hi, dim3(2048), dim3(256), 0, stream,
                       u, v_t, w3fh, w3fl, mb1, mb2, mb3, lw0t, lb0, lw1t, lb1, out);
}